// Round 1
// baseline (3238.208 us; speedup 1.0000x reference)
//
#include <hip/hip_runtime.h>

// ---------------- constants ----------------
#define NTOK 4096         // B*P patches
#define CH   512          // patches per stage-2 chunk
#define NCHUNK 8

typedef _Float16 f16;
typedef __attribute__((ext_vector_type(8))) _Float16 half8;
typedef __attribute__((ext_vector_type(4))) _Float16 half4;
typedef __attribute__((ext_vector_type(4))) float f32x4;

// converted-weight layout (f16 elements) inside workspace
#define OFF_INPW 0
#define OFF_WQ   (512*96)
#define OFF_WK   (OFF_WQ + 512*512)
#define OFF_WV   (OFF_WK + 512*512)
#define OFF_WO   (OFF_WV + 512*512)
#define OFF_W1   (OFF_WO + 512*512)
#define OFF_W2   (OFF_W1 + 512*512)
#define OFF_GW   (OFF_W2 + 512*512)       // 8 matrices: gwq0,gwq1,gwk0,gwk1,gwv0,gwv1,gwo0,gwo1
#define WBF_TOT  (OFF_GW + 8*512*512)

static __device__ __forceinline__ f32x4 mfma16(half8 a, half8 b, f32x4 c){
  return __builtin_amdgcn_mfma_f32_16x16x32_f16(a, b, c, 0, 0, 0);
}

// ---------------- weight conversion (f32 -> f16, inp_w padded 80->96) ----------------
__global__ __launch_bounds__(256) void conv_weights(
    const float* __restrict__ inpw, const float* __restrict__ wq, const float* __restrict__ wk,
    const float* __restrict__ wv, const float* __restrict__ wo, const float* __restrict__ w1,
    const float* __restrict__ w2, const float* __restrict__ gwq, const float* __restrict__ gwk,
    const float* __restrict__ gwv, const float* __restrict__ gwo, f16* __restrict__ wbf)
{
  int e = blockIdx.x*256 + threadIdx.x;
  int y = blockIdx.y;
  if (y == 0){
    if (e < 512*96){
      int row = e/96, col = e - row*96;
      float v = (col < 80) ? inpw[row*80 + col] : 0.f;
      wbf[OFF_INPW + e] = (f16)v;
    }
    return;
  }
  if (e >= 512*512) return;
  const float* src; int off;
  if (y <= 6){
    const float* tab[6] = {wq, wk, wv, wo, w1, w2};
    src = tab[y-1]; off = OFF_WQ + (y-1)*512*512;
  } else {
    int idx = y-7; int mat = idx>>1, li = idx&1;
    const float* tab[4] = {gwq, gwk, gwv, gwo};
    src = tab[mat] + (size_t)li*512*512; off = OFF_GW + idx*512*512;
  }
  wbf[off + e] = (f16)src[e];
}

// ---------------- per-patch mask aux: key-pad bias + pexists ----------------
__global__ __launch_bounds__(256) void build_mask(
    const int* __restrict__ mask, float* __restrict__ mb, float* __restrict__ pex)
{
  int wv = threadIdx.x>>6, lane = threadIdx.x&63;
  int n = blockIdx.x*4 + wv;
  int valid = mask[(size_t)n*64 + lane] > 0;
  unsigned long long ball = __ballot(valid);
  int hasany = (ball != 0ull);
  int masked = (lane == 0) ? (!valid && hasany) : (!valid);
  mb[(size_t)n*64 + lane] = masked ? -1e9f : 0.f;
  if (lane == 0) pex[n] = hasany ? 1.f : 0.f;
}

// ---------------- pts: [x | te1 | sin(te2) | 0-pad] -> f16 [rows][96] ----------------
__global__ __launch_bounds__(256) void pts_build(
    const float* __restrict__ x, const float* __restrict__ tt,
    const float* __restrict__ tsw, const float* __restrict__ tsb,
    const float* __restrict__ tpw, const float* __restrict__ tpb,
    f16* __restrict__ pts, int rowbase)
{
  int e = blockIdx.x*256 + threadIdx.x;        // CH*64*96 exact
  int r = e/96, col = e - r*96;
  size_t grow = (size_t)rowbase + r;
  float v;
  if (col < 16) v = x[grow*16 + col];
  else {
    float t = tt[grow];
    if (col == 16)      v = t*tsw[0] + tsb[0];
    else if (col < 80)  v = __sinf(t*tpw[col-17] + tpb[col-17]);
    else                v = 0.f;
  }
  pts[e] = (f16)v;
}

// ---------------- MFMA GEMM: C[M,512] = A[M,K] @ W[512,K]^T (+bias, fused epilogues) ----
// RESID: 0 none, 1 += f16 residual, 2 (v+bias)*pex[row] + f32 residual (stage-3)
template<int RESID, bool RELU, bool OUTF32, bool ZEMPTY>
__global__ __launch_bounds__(256) void gemm_bt(
    const f16* __restrict__ A, const f16* __restrict__ W, const float* __restrict__ bias,
    void* __restrict__ Cout, const void* __restrict__ Rsd, const float* __restrict__ pex,
    int K, int nbase)
{
  __shared__ f16 As[64][40];
  __shared__ f16 Ws[64][40];
  const int tid = threadIdx.x;
  const int m0 = blockIdx.x*64, n0 = blockIdx.y*64;
  const int wv = tid>>6, lane = tid&63, l15 = lane&15, quad = lane>>4;
  const int r = tid>>2, c8 = (tid&3)*8;
  f32x4 acc[4] = {};
  for (int kc = 0; kc < K; kc += 32){
    __syncthreads();
    *(uint4*)(&As[r][c8]) = *(const uint4*)(A + (size_t)(m0+r)*K + kc + c8);
    *(uint4*)(&Ws[r][c8]) = *(const uint4*)(W + (size_t)(n0+r)*K + kc + c8);
    __syncthreads();
    half8 a = *(const half8*)(&As[wv*16 + l15][quad*8]);
    #pragma unroll
    for (int nt=0; nt<4; nt++){
      half8 b = *(const half8*)(&Ws[nt*16 + l15][quad*8]);
      acc[nt] = mfma16(a, b, acc[nt]);
    }
  }
  #pragma unroll
  for (int nt=0; nt<4; nt++){
    #pragma unroll
    for (int i=0; i<4; i++){
      int gr = m0 + wv*16 + quad*4 + i;
      int gc = n0 + nt*16 + l15;
      float v = acc[nt][i] + bias[gc];
      if (RELU) v = v > 0.f ? v : 0.f;
      if (RESID == 1) v += (float)((const f16*)Rsd)[(size_t)gr*512 + gc];
      if (ZEMPTY){ if (pex[nbase + (gr>>6)] == 0.f && (gr&63) == 0) v = 0.f; }
      if (RESID == 2) v = v * pex[gr] + ((const float*)Rsd)[(size_t)gr*512 + gc];
      if (OUTF32) ((float*)Cout)[(size_t)gr*512 + gc] = v;
      else        ((f16*)Cout)[(size_t)gr*512 + gc] = (f16)v;
    }
  }
}

// ---------------- intra-patch MHA: one wave per (patch, head), L=64 ----------------
__global__ __launch_bounds__(128) void attn_patch(
    const f16* __restrict__ Q, const f16* __restrict__ Kb, const f16* __restrict__ Vb,
    f16* __restrict__ Z, const float* __restrict__ maskbias, int nbase)
{
  __shared__ f16 Vt[2][64][72];   // V^T [d][key]; later reused as z [q][d]
  __shared__ f16 Ps[2][64][72];   // softmax probs [q][key]
  __shared__ float mbs[64];
  const int tid = threadIdx.x, wv = tid>>6, lane = tid&63, l15 = lane&15, quad = lane>>4;
  const int n = blockIdx.x, h = blockIdx.y*2 + wv;
  if (tid < 64) mbs[tid] = maskbias[(size_t)(nbase+n)*64 + tid];
  for (int i=0; i<64; i++)   // V transpose into LDS (coalesced global read)
    Vt[wv][lane][i] = Vb[((size_t)n*64 + i)*512 + h*64 + lane];
  __syncthreads();
  const f16* Qb  = Q  + (size_t)n*64*512 + h*64;
  const f16* Kbb = Kb + (size_t)n*64*512 + h*64;
  f32x4 sacc[4][4] = {};
  #pragma unroll
  for (int kc=0; kc<2; kc++){
    half8 af[4], bf[4];
    #pragma unroll
    for (int t4=0; t4<4; t4++){
      af[t4] = *(const half8*)(Qb  + (size_t)(t4*16 + l15)*512 + kc*32 + quad*8);
      bf[t4] = *(const half8*)(Kbb + (size_t)(t4*16 + l15)*512 + kc*32 + quad*8);
    }
    #pragma unroll
    for (int ti=0; ti<4; ti++)
      #pragma unroll
      for (int tj=0; tj<4; tj++)
        sacc[ti][tj] = mfma16(af[ti], bf[tj], sacc[ti][tj]);
  }
  // softmax over keys; row's 64 cols live in the 16 lanes of this quad (4 regs each)
  #pragma unroll
  for (int ti=0; ti<4; ti++){
    #pragma unroll
    for (int i=0; i<4; i++){
      float mx = -1e30f;
      #pragma unroll
      for (int tj=0; tj<4; tj++){
        float sv = sacc[ti][tj][i]*0.125f + mbs[tj*16 + l15];
        sacc[ti][tj][i] = sv;
        mx = fmaxf(mx, sv);
      }
      #pragma unroll
      for (int off=1; off<16; off<<=1) mx = fmaxf(mx, __shfl_xor(mx, off, 64));
      float sum = 0.f;
      #pragma unroll
      for (int tj=0; tj<4; tj++){
        float pv = __expf(sacc[ti][tj][i] - mx);
        sacc[ti][tj][i] = pv; sum += pv;
      }
      #pragma unroll
      for (int off=1; off<16; off<<=1) sum += __shfl_xor(sum, off, 64);
      float inv = 1.f/sum;
      int q = ti*16 + quad*4 + i;
      #pragma unroll
      for (int tj=0; tj<4; tj++)
        Ps[wv][q][tj*16 + l15] = (f16)(sacc[ti][tj][i]*inv);
    }
  }
  __syncthreads();
  // z^T = V^T @ P^T  (both operands in [x][k] frag form)
  f32x4 zacc[4][4] = {};
  #pragma unroll
  for (int kc=0; kc<2; kc++){
    half8 va[4], pb[4];
    #pragma unroll
    for (int t4=0; t4<4; t4++){
      va[t4] = *(const half8*)(&Vt[wv][t4*16 + l15][kc*32 + quad*8]);
      pb[t4] = *(const half8*)(&Ps[wv][t4*16 + l15][kc*32 + quad*8]);
    }
    #pragma unroll
    for (int ti2=0; ti2<4; ti2++)
      #pragma unroll
      for (int tj=0; tj<4; tj++)
        zacc[ti2][tj] = mfma16(va[ti2], pb[tj], zacc[ti2][tj]);
  }
  __syncthreads();
  #pragma unroll
  for (int ti2=0; ti2<4; ti2++)
    #pragma unroll
    for (int tj=0; tj<4; tj++){
      int q = tj*16 + l15, d0 = ti2*16 + quad*4;
      half4 pk;
      #pragma unroll
      for (int i=0; i<4; i++) pk[i] = (f16)zacc[ti2][tj][i];
      *(half4*)(&Vt[wv][q][d0]) = pk;     // z staged [q][d]
    }
  __syncthreads();
  #pragma unroll
  for (int i=0; i<8; i++){
    int q = i*8 + (lane>>3), d0 = (lane&7)*8;
    *(uint4*)(Z + ((size_t)n*64 + q)*512 + h*64 + d0) = *(const uint4*)(&Vt[wv][q][d0]);
  }
}

// ---------------- LayerNorm over rows of 512 (wave per row) ----------------
__global__ __launch_bounds__(256) void ln_rows(
    const f16* __restrict__ X, f16* __restrict__ Y,
    const float* __restrict__ g, const float* __restrict__ b)
{
  int wv = threadIdx.x>>6, lane = threadIdx.x&63;
  size_t row = (size_t)blockIdx.x*4 + wv;
  half8 raw = *(const half8*)(X + row*512 + lane*8);
  float xv[8];
  #pragma unroll
  for (int j=0; j<8; j++) xv[j] = (float)raw[j];
  float s = 0.f;
  #pragma unroll
  for (int j=0; j<8; j++) s += xv[j];
  #pragma unroll
  for (int off=1; off<64; off<<=1) s += __shfl_xor(s, off, 64);
  float mean = s*(1.f/512.f);
  float vs = 0.f;
  #pragma unroll
  for (int j=0; j<8; j++){ float d = xv[j]-mean; vs += d*d; }
  #pragma unroll
  for (int off=1; off<64; off<<=1) vs += __shfl_xor(vs, off, 64);
  float rstd = rsqrtf(vs*(1.f/512.f) + 1e-5f);
  half8 o;
  #pragma unroll
  for (int j=0; j<8; j++){
    int c = lane*8 + j;
    o[j] = (f16)((xv[j]-mean)*rstd*g[c] + b[c]);
  }
  *(half8*)(Y + row*512 + lane*8) = o;
}

// ---------------- LN2 + masked mean pool + exists_bias + pos-encoding ----------------
__global__ __launch_bounds__(256) void pool_ln2(
    const f16* __restrict__ X, const int* __restrict__ mask,
    const float* __restrict__ g, const float* __restrict__ b, const float* __restrict__ eb,
    float* __restrict__ out, int nbase)
{
  __shared__ float mArr[64], rArr[64], vArr[64];
  const int tid = threadIdx.x, wv = tid>>6, lane = tid&63;
  const int n = blockIdx.x, ng = nbase + n, p = ng & 127;
  for (int j=0; j<16; j++){
    int l = wv*16 + j;
    half8 raw = *(const half8*)(X + ((size_t)n*64 + l)*512 + lane*8);
    float s=0.f, ss=0.f;
    #pragma unroll
    for (int jj=0; jj<8; jj++){ float f = (float)raw[jj]; s += f; ss += f*f; }
    #pragma unroll
    for (int off=1; off<64; off<<=1){ s += __shfl_xor(s, off, 64); ss += __shfl_xor(ss, off, 64); }
    if (lane == 0){
      float m = s*(1.f/512.f);
      mArr[l] = m; rArr[l] = rsqrtf(ss*(1.f/512.f) - m*m + 1e-5f);
    }
  }
  if (tid < 64) vArr[tid] = (mask[(size_t)ng*64 + tid] > 0) ? 1.f : 0.f;
  __syncthreads();
  float cnt = 0.f;
  #pragma unroll
  for (int l=0; l<64; l++) cnt += vArr[l];
  float denom = fmaxf(cnt, 1.f);
  float pexv = cnt > 0.f ? 1.f : 0.f;
  float a0=0.f, a1=0.f;
  for (int l=0; l<64; l++){
    float wgt = vArr[l], m = mArr[l], rs = rArr[l];
    float x0 = (float)X[((size_t)n*64+l)*512 + tid];
    float x1 = (float)X[((size_t)n*64+l)*512 + tid + 256];
    a0 += wgt*(x0-m)*rs; a1 += wgt*(x1-m)*rs;
  }
  #pragma unroll
  for (int k=0; k<2; k++){
    int c = tid + k*256;
    float acc = k ? a1 : a0;
    float fr = __expf(-(float)(c & ~1) * (9.210340371976184f/512.f));
    float ang = (float)p * fr;
    float pe = (c & 1) ? cosf(ang) : sinf(ang);
    float o = (g[c]*acc + b[c]*cnt)/denom + eb[c]*(1.f - pexv) + pe;
    out[(size_t)ng*512 + c] = o;
  }
}

__global__ __launch_bounds__(256) void cvt_f32_f16(const float* __restrict__ s, f16* __restrict__ d){
  int i = blockIdx.x*256 + threadIdx.x;
  d[i] = (f16)s[i];
}

// ---------------- graph attention: block per (batch, head), P=128 keys ----------------
__global__ __launch_bounds__(256) void attn_graph(
    const f16* __restrict__ Q, const f16* __restrict__ Kb, const f16* __restrict__ Vb,
    f16* __restrict__ Z, const float* __restrict__ pexists)
{
  __shared__ f16 Vt[64][136];        // V^T [d][key]
  __shared__ f16 Ps[4][32][136];     // per-wave probs [q_local][key]; reused for z
  __shared__ float pxs[128];
  const int tid = threadIdx.x, wv = tid>>6, lane = tid&63, l15 = lane&15, quad = lane>>4;
  const int b = blockIdx.x, h = blockIdx.y;
  if (tid < 128) pxs[tid] = pexists[b*128 + tid];
  for (int i=0; i<32; i++){
    int e = tid + i*256, k = e>>6, d = e&63;
    Vt[d][k] = Vb[((size_t)b*128 + k)*512 + h*64 + d];
  }
  __syncthreads();
  const int qb = wv*32;
  f32x4 sacc[2][8] = {};
  #pragma unroll
  for (int kc=0; kc<2; kc++){
    half8 af[2], bf[8];
    #pragma unroll
    for (int ti=0; ti<2; ti++)
      af[ti] = *(const half8*)(Q + ((size_t)b*128 + qb + ti*16 + l15)*512 + h*64 + kc*32 + quad*8);
    #pragma unroll
    for (int tj=0; tj<8; tj++)
      bf[tj] = *(const half8*)(Kb + ((size_t)b*128 + tj*16 + l15)*512 + h*64 + kc*32 + quad*8);
    #pragma unroll
    for (int ti=0; ti<2; ti++)
      #pragma unroll
      for (int tj=0; tj<8; tj++)
        sacc[ti][tj] = mfma16(af[ti], bf[tj], sacc[ti][tj]);
  }
  // scale + time-bias + key-pad, then softmax over 128 keys
  #pragma unroll
  for (int ti=0; ti<2; ti++){
    #pragma unroll
    for (int i=0; i<4; i++){
      int q = qb + ti*16 + quad*4 + i;
      float mx = -1e30f;
      #pragma unroll
      for (int tj=0; tj<8; tj++){
        int col = tj*16 + l15;
        int dd = q - col; if (dd < 0) dd = -dd;
        float tb = __logf(__expf(-(float)dd) + 1e-12f);
        float sv = sacc[ti][tj][i]*0.125f + tb + (pxs[col] > 0.f ? 0.f : -1e9f);
        sacc[ti][tj][i] = sv;
        mx = fmaxf(mx, sv);
      }
      #pragma unroll
      for (int off=1; off<16; off<<=1) mx = fmaxf(mx, __shfl_xor(mx, off, 64));
      float sum = 0.f;
      #pragma unroll
      for (int tj=0; tj<8; tj++){
        float pv = __expf(sacc[ti][tj][i] - mx);
        sacc[ti][tj][i] = pv; sum += pv;
      }
      #pragma unroll
      for (int off=1; off<16; off<<=1) sum += __shfl_xor(sum, off, 64);
      float inv = 1.f/sum;
      int ql = ti*16 + quad*4 + i;
      #pragma unroll
      for (int tj=0; tj<8; tj++)
        Ps[wv][ql][tj*16 + l15] = (f16)(sacc[ti][tj][i]*inv);
    }
  }
  __syncthreads();
  f32x4 zacc[4][2] = {};
  #pragma unroll
  for (int kc=0; kc<4; kc++){
    half8 va[4], pb[2];
    #pragma unroll
    for (int ti2=0; ti2<4; ti2++)
      va[ti2] = *(const half8*)(&Vt[ti2*16 + l15][kc*32 + quad*8]);
    #pragma unroll
    for (int tjq=0; tjq<2; tjq++)
      pb[tjq] = *(const half8*)(&Ps[wv][tjq*16 + l15][kc*32 + quad*8]);
    #pragma unroll
    for (int ti2=0; ti2<4; ti2++)
      #pragma unroll
      for (int tjq=0; tjq<2; tjq++)
        zacc[ti2][tjq] = mfma16(va[ti2], pb[tjq], zacc[ti2][tjq]);
  }
  __syncthreads();
  #pragma unroll
  for (int ti2=0; ti2<4; ti2++)
    #pragma unroll
    for (int tjq=0; tjq<2; tjq++){
      int ql = tjq*16 + l15, d0 = ti2*16 + quad*4;
      half4 pk;
      #pragma unroll
      for (int i=0; i<4; i++) pk[i] = (f16)zacc[ti2][tjq][i];
      *(half4*)(&Ps[wv][ql][d0]) = pk;    // z staged [q_local][d]
    }
  __syncthreads();
  {
    int q = tid>>1, hf = tid&1;
    const f16* src = &Ps[q>>5][q&31][hf*32];
    #pragma unroll
    for (int j=0; j<4; j++)
      *(uint4*)(Z + ((size_t)b*128 + q)*512 + h*64 + hf*32 + j*8) = *(const uint4*)(src + j*8);
  }
}

// ---------------- launcher ----------------
extern "C" void kernel_launch(void* const* d_in, const int* in_sizes, int n_in,
                              void* d_out, int out_size, void* d_ws, size_t ws_size,
                              hipStream_t stream)
{
  (void)in_sizes; (void)n_in; (void)out_size; (void)ws_size;
  const float* x    = (const float*)d_in[0];
  const float* tt   = (const float*)d_in[1];
  const int*   mask = (const int*)  d_in[2];
  const float* tsw  = (const float*)d_in[3];
  const float* tsb  = (const float*)d_in[4];
  const float* tpw  = (const float*)d_in[5];
  const float* tpb  = (const float*)d_in[6];
  const float* inpw = (const float*)d_in[7];
  const float* inpb = (const float*)d_in[8];
  const float* wq   = (const float*)d_in[9];
  const float* bq   = (const float*)d_in[10];
  const float* wk   = (const float*)d_in[11];
  const float* bk   = (const float*)d_in[12];
  const float* wv   = (const float*)d_in[13];
  const float* bv   = (const float*)d_in[14];
  const float* wo   = (const float*)d_in[15];
  const float* bo   = (const float*)d_in[16];
  const float* w1   = (const float*)d_in[17];
  const float* b1   = (const float*)d_in[18];
  const float* w2   = (const float*)d_in[19];
  const float* b2   = (const float*)d_in[20];
  const float* ln1g = (const float*)d_in[21];
  const float* ln1b = (const float*)d_in[22];
  const float* ln2g = (const float*)d_in[23];
  const float* ln2b = (const float*)d_in[24];
  const float* eb   = (const float*)d_in[25];
  const float* gwq  = (const float*)d_in[26];
  const float* gbq  = (const float*)d_in[27];
  const float* gwk  = (const float*)d_in[28];
  const float* gbk  = (const float*)d_in[29];
  const float* gwv  = (const float*)d_in[30];
  const float* gbv  = (const float*)d_in[31];
  const float* gwo  = (const float*)d_in[32];
  const float* gbo  = (const float*)d_in[33];
  float* out = (float*)d_out;

  char* wp = (char*)d_ws;
  auto alloc = [&](size_t bytes)->char*{
    char* p = wp; wp += (bytes + 255) & ~(size_t)255; return p;
  };
  f16*   wbf  = (f16*)  alloc((size_t)WBF_TOT*2);
  float* mb   = (float*)alloc((size_t)NTOK*64*4);
  float* pex  = (float*)alloc((size_t)NTOK*4);
  f16*   ptsb = (f16*)  alloc((size_t)CH*64*96*2);
  f16*   bufA = (f16*)  alloc((size_t)CH*64*512*2);
  f16*   bufB = (f16*)  alloc((size_t)CH*64*512*2);
  f16*   bufC = (f16*)  alloc((size_t)CH*64*512*2);
  f16*   bufD = (f16*)  alloc((size_t)CH*64*512*2);
  f16*   bufE = (f16*)  alloc((size_t)CH*64*512*2);
  f16*   hbf  = (f16*)  alloc((size_t)NTOK*512*2);
  f16*   qg   = (f16*)  alloc((size_t)NTOK*512*2);
  f16*   kg   = (f16*)  alloc((size_t)NTOK*512*2);
  f16*   vg   = (f16*)  alloc((size_t)NTOK*512*2);
  f16*   zg   = (f16*)  alloc((size_t)NTOK*512*2);
  // total ~194 MiB

  conv_weights<<<dim3(1024,15),256,0,stream>>>(inpw,wq,wk,wv,wo,w1,w2,gwq,gwk,gwv,gwo,wbf);
  build_mask<<<NTOK/4,256,0,stream>>>(mask, mb, pex);

  for (int ch=0; ch<NCHUNK; ch++){
    int nbase = ch*CH;
    int rowbase = nbase*64;
    pts_build<<<CH*64*96/256,256,0,stream>>>(x,tt,tsw,tsb,tpw,tpb,ptsb,rowbase);
    // h0 = pts @ inp_w^T + b (zero row0 of empty patches)
    gemm_bt<0,false,false,true ><<<dim3(CH*64/64,8),256,0,stream>>>(ptsb, wbf+OFF_INPW, inpb, bufA, nullptr, pex, 96, nbase);
    // q,k,v
    gemm_bt<0,false,false,false><<<dim3(CH*64/64,8),256,0,stream>>>(bufA, wbf+OFF_WQ, bq, bufB, nullptr, nullptr, 512, 0);
    gemm_bt<0,false,false,false><<<dim3(CH*64/64,8),256,0,stream>>>(bufA, wbf+OFF_WK, bk, bufC, nullptr, nullptr, 512, 0);
    gemm_bt<0,false,false,false><<<dim3(CH*64/64,8),256,0,stream>>>(bufA, wbf+OFF_WV, bv, bufD, nullptr, nullptr, 512, 0);
    attn_patch<<<dim3(CH,4),128,0,stream>>>(bufB, bufC, bufD, bufE, mb, nbase);
    // out-proj + residual(h0), in place on bufA
    gemm_bt<1,false,false,false><<<dim3(CH*64/64,8),256,0,stream>>>(bufE, wbf+OFF_WO, bo, bufA, bufA, nullptr, 512, 0);
    ln_rows<<<CH*64/4,256,0,stream>>>(bufA, bufB, ln1g, ln1b);
    gemm_bt<0,true ,false,false><<<dim3(CH*64/64,8),256,0,stream>>>(bufB, wbf+OFF_W1, b1, bufC, nullptr, nullptr, 512, 0);
    gemm_bt<1,false,false,false><<<dim3(CH*64/64,8),256,0,stream>>>(bufC, wbf+OFF_W2, b2, bufD, bufB, nullptr, 512, 0);
    pool_ln2<<<CH,256,0,stream>>>(bufD, mask, ln2g, ln2b, eb, out, nbase);
  }

  for (int li=0; li<2; li++){
    cvt_f32_f16<<<NTOK*512/256,256,0,stream>>>(out, hbf);
    gemm_bt<0,false,false,false><<<dim3(64,8),256,0,stream>>>(hbf, wbf+OFF_GW + (size_t)(0*2+li)*512*512, gbq+li*512, qg, nullptr, nullptr, 512, 0);
    gemm_bt<0,false,false,false><<<dim3(64,8),256,0,stream>>>(hbf, wbf+OFF_GW + (size_t)(1*2+li)*512*512, gbk+li*512, kg, nullptr, nullptr, 512, 0);
    gemm_bt<0,false,false,false><<<dim3(64,8),256,0,stream>>>(hbf, wbf+OFF_GW + (size_t)(2*2+li)*512*512, gbv+li*512, vg, nullptr, nullptr, 512, 0);
    attn_graph<<<dim3(32,8),256,0,stream>>>(qg, kg, vg, zg, pex);
    // h += (z @ gwo^T + gbo) * pexists   (in place on f32 d_out)
    gemm_bt<2,false,true ,false><<<dim3(64,8),256,0,stream>>>(zg, wbf+OFF_GW + (size_t)(3*2+li)*512*512, gbo+li*512, out, out, pex, 512, 0);
  }
}

// Round 2
// 2398.370 us; speedup vs baseline: 1.3502x; 1.3502x over previous
//
#include <hip/hip_runtime.h>

// ---------------- constants ----------------
#define NTOK 4096         // B*P patches
#define CH   512          // patches per stage-2 chunk
#define NCHUNK 8

typedef _Float16 f16;
typedef __attribute__((ext_vector_type(8))) _Float16 half8;
typedef __attribute__((ext_vector_type(4))) _Float16 half4;
typedef __attribute__((ext_vector_type(4))) float f32x4;

// converted-weight layout (f16 elements) inside workspace
// inp_w padded 80->128 cols; stage-2 qkv contiguous; per-layer graph [qkv|wo]
#define OFF_INPW 0
#define OFF_WQKV (512*128)
#define OFF_WO   (OFF_WQKV + 3*512*512)
#define OFF_W1   (OFF_WO + 512*512)
#define OFF_W2   (OFF_W1 + 512*512)
#define OFF_GW   (OFF_W2 + 512*512)       // 2 layers x [gwq|gwk|gwv|gwo]
#define WBF_TOT  (OFF_GW + 8*512*512)

static __device__ __forceinline__ f32x4 mfma16(half8 a, half8 b, f32x4 c){
  return __builtin_amdgcn_mfma_f32_16x16x32_f16(a, b, c, 0, 0, 0);
}

static __device__ __forceinline__ void gld_lds16(const f16* g, f16* l){
  __builtin_amdgcn_global_load_lds(
      (const __attribute__((address_space(1))) void*)g,
      (__attribute__((address_space(3))) void*)l, 16, 0, 0);
}

// ---------------- weight conversion ----------------
__global__ __launch_bounds__(256) void conv_weights(
    const float* __restrict__ inpw, const float* __restrict__ wq, const float* __restrict__ wk,
    const float* __restrict__ wv, const float* __restrict__ wo, const float* __restrict__ w1,
    const float* __restrict__ w2, const float* __restrict__ gwq, const float* __restrict__ gwk,
    const float* __restrict__ gwv, const float* __restrict__ gwo, f16* __restrict__ wbf,
    const float* __restrict__ bq, const float* __restrict__ bk, const float* __restrict__ bv,
    const float* __restrict__ gbq, const float* __restrict__ gbk, const float* __restrict__ gbv,
    float* __restrict__ biasb)
{
  int e = blockIdx.x*256 + threadIdx.x;
  int y = blockIdx.y;
  if (y == 0){
    if (e < 512*128){
      int row = e>>7, col = e&127;
      float v = (col < 80) ? inpw[row*80 + col] : 0.f;
      wbf[OFF_INPW + e] = (f16)v;
    }
    return;
  }
  if (y == 15){
    // merged biases: [s2 qkv 1536][layer0 qkv 1536][layer1 qkv 1536]
    if (e < 1536){
      biasb[e] = (e < 512) ? bq[e] : (e < 1024 ? bk[e-512] : bv[e-1024]);
    } else if (e < 3*1536){
      int idx = e - 1536, li = idx/1536, c = idx - li*1536;
      float v = (c < 512) ? gbq[li*512 + c] : (c < 1024 ? gbk[li*512 + c-512] : gbv[li*512 + c-1024]);
      biasb[e] = v;
    }
    return;
  }
  if (e >= 512*512) return;
  const float* src; int off;
  if (y <= 6){
    const float* tab[6] = {wq, wk, wv, wo, w1, w2};
    src = tab[y-1]; off = OFF_WQKV + (y-1)*512*512;
  } else {
    int idx = y-7; int li = idx>>2, part = idx&3;
    const float* tab[4] = {gwq, gwk, gwv, gwo};
    src = tab[part] + (size_t)li*512*512; off = OFF_GW + idx*512*512;
  }
  wbf[off + e] = (f16)src[e];
}

// ---------------- per-patch mask aux ----------------
__global__ __launch_bounds__(256) void build_mask(
    const int* __restrict__ mask, float* __restrict__ mb, float* __restrict__ pex)
{
  int wv = threadIdx.x>>6, lane = threadIdx.x&63;
  int n = blockIdx.x*4 + wv;
  int valid = mask[(size_t)n*64 + lane] > 0;
  unsigned long long ball = __ballot(valid);
  int hasany = (ball != 0ull);
  int masked = (lane == 0) ? (!valid && hasany) : (!valid);
  mb[(size_t)n*64 + lane] = masked ? -1e9f : 0.f;
  if (lane == 0) pex[n] = hasany ? 1.f : 0.f;
}

// ---------------- pts: [x | te1 | sin(te2) | 0-pad] -> f16 [rows][128] ----------------
__global__ __launch_bounds__(256) void pts_build(
    const float* __restrict__ x, const float* __restrict__ tt,
    const float* __restrict__ tsw, const float* __restrict__ tsb,
    const float* __restrict__ tpw, const float* __restrict__ tpb,
    f16* __restrict__ pts, int rowbase)
{
  int e = blockIdx.x*256 + threadIdx.x;        // CH*64*128 exact
  int r = e>>7, col = e&127;
  size_t grow = (size_t)rowbase + r;
  float v;
  if (col < 16) v = x[grow*16 + col];
  else if (col >= 80) v = 0.f;
  else {
    float t = tt[grow];
    if (col == 16) v = t*tsw[0] + tsb[0];
    else           v = __sinf(t*tpw[col-17] + tpb[col-17]);
  }
  pts[e] = (f16)v;
}

// ---------------- MFMA GEMM: C[M,*] = A[M,K](lda) @ W[N,K]^T, 128x128 tile ----------
// global_load_lds(16) staging with XOR-swizzled LDS layout (conflict-free frag reads).
// RESID: 0 none, 1 += f16 residual, 2 (v+bias)*pex[row] + f32 residual (stage-3)
template<int RESID, bool RELU, bool OUTF32, bool ZEMPTY>
__global__ __launch_bounds__(256) void gemm128(
    const f16* __restrict__ A, const f16* __restrict__ W, const float* __restrict__ bias,
    void* __restrict__ Cout, const void* __restrict__ Rsd, const float* __restrict__ pex,
    int K, int lda, int ldc, int nbase)
{
  __shared__ __align__(16) f16 As[128][64];
  __shared__ __align__(16) f16 Bs[128][64];
  const int tid = threadIdx.x;
  const int m0 = blockIdx.x*128, n0 = blockIdx.y*128;
  const int wv = tid>>6, lane = tid&63, l15 = lane&15, quad = lane>>4;
  const int wm = (wv&1)*64, wn = (wv>>1)*64;
  const int srow = lane>>3;                 // row within 8-row group
  const int schunk = (lane&7) ^ srow;       // swizzled source chunk
  f32x4 acc[4][4] = {};
  for (int kc = 0; kc < K; kc += 64){
    __syncthreads();
    #pragma unroll
    for (int i=0; i<4; i++){
      const int rA = wv*32 + i*8;
      gld_lds16(A + (size_t)(m0 + rA + srow)*lda + kc + schunk*8, &As[rA][0]);
      gld_lds16(W + (size_t)(n0 + rA + srow)*K   + kc + schunk*8, &Bs[rA][0]);
    }
    __syncthreads();   // drains vmcnt (global_load_lds) + lgkm
    #pragma unroll
    for (int kk=0; kk<2; kk++){
      half8 av[4], bv8[4];
      #pragma unroll
      for (int t=0; t<4; t++){
        const int ra = wm + t*16 + l15;
        av[t]  = *(const half8*)(&As[ra][(((kk*4 + quad) ^ (ra&7)))*8]);
        const int rb = wn + t*16 + l15;
        bv8[t] = *(const half8*)(&Bs[rb][(((kk*4 + quad) ^ (rb&7)))*8]);
      }
      #pragma unroll
      for (int mt=0; mt<4; mt++)
        #pragma unroll
        for (int nt=0; nt<4; nt++)
          acc[mt][nt] = mfma16(av[mt], bv8[nt], acc[mt][nt]);
    }
  }
  #pragma unroll
  for (int mt=0; mt<4; mt++){
    #pragma unroll
    for (int nt=0; nt<4; nt++){
      #pragma unroll
      for (int i=0; i<4; i++){
        int gr = m0 + wm + mt*16 + quad*4 + i;
        int gc = n0 + wn + nt*16 + l15;
        float v = acc[mt][nt][i] + bias[gc];
        if (RELU) v = fmaxf(v, 0.f);
        if (RESID == 1) v += (float)((const f16*)Rsd)[(size_t)gr*ldc + gc];
        if (ZEMPTY){ if ((gr&63)==0 && pex[nbase + (gr>>6)]==0.f) v = 0.f; }
        if (RESID == 2) v = v*pex[gr] + ((const float*)Rsd)[(size_t)gr*ldc + gc];
        if (OUTF32) ((float*)Cout)[(size_t)gr*ldc + gc] = v;
        else        ((f16*)Cout)[(size_t)gr*ldc + gc] = (f16)v;
      }
    }
  }
}

// ---------------- intra-patch MHA on merged QKV buffer (stride 1536) ----------------
// Z written in place over the Q region (disjoint columns per block; reads precede writes).
__global__ __launch_bounds__(128) void attn_patch(
    f16* __restrict__ qkv, const float* __restrict__ maskbias, int nbase)
{
  __shared__ f16 Vt[2][64][72];   // V^T [d][key]; later reused as z [q][d]
  __shared__ f16 Ps[2][64][72];   // softmax probs [q][key]
  __shared__ float mbs[64];
  const int tid = threadIdx.x, wv = tid>>6, lane = tid&63, l15 = lane&15, quad = lane>>4;
  const int n = blockIdx.x, h = blockIdx.y*2 + wv;
  if (tid < 64) mbs[tid] = maskbias[(size_t)(nbase+n)*64 + tid];
  const f16* Vb = qkv + 1024 + h*64;
  for (int i=0; i<64; i++)
    Vt[wv][lane][i] = Vb[((size_t)n*64 + i)*1536 + lane];
  __syncthreads();
  const f16* Qb  = qkv + (size_t)n*64*1536 + h*64;
  const f16* Kbb = Qb + 512;
  f32x4 sacc[4][4] = {};
  #pragma unroll
  for (int kc=0; kc<2; kc++){
    half8 af[4], bf[4];
    #pragma unroll
    for (int t4=0; t4<4; t4++){
      af[t4] = *(const half8*)(Qb  + (size_t)(t4*16 + l15)*1536 + kc*32 + quad*8);
      bf[t4] = *(const half8*)(Kbb + (size_t)(t4*16 + l15)*1536 + kc*32 + quad*8);
    }
    #pragma unroll
    for (int ti=0; ti<4; ti++)
      #pragma unroll
      for (int tj=0; tj<4; tj++)
        sacc[ti][tj] = mfma16(af[ti], bf[tj], sacc[ti][tj]);
  }
  #pragma unroll
  for (int ti=0; ti<4; ti++){
    #pragma unroll
    for (int i=0; i<4; i++){
      float mx = -1e30f;
      #pragma unroll
      for (int tj=0; tj<4; tj++){
        float sv = sacc[ti][tj][i]*0.125f + mbs[tj*16 + l15];
        sacc[ti][tj][i] = sv;
        mx = fmaxf(mx, sv);
      }
      #pragma unroll
      for (int off=1; off<16; off<<=1) mx = fmaxf(mx, __shfl_xor(mx, off, 64));
      float sum = 0.f;
      #pragma unroll
      for (int tj=0; tj<4; tj++){
        float pv = __expf(sacc[ti][tj][i] - mx);
        sacc[ti][tj][i] = pv; sum += pv;
      }
      #pragma unroll
      for (int off=1; off<16; off<<=1) sum += __shfl_xor(sum, off, 64);
      float inv = 1.f/sum;
      int q = ti*16 + quad*4 + i;
      #pragma unroll
      for (int tj=0; tj<4; tj++)
        Ps[wv][q][tj*16 + l15] = (f16)(sacc[ti][tj][i]*inv);
    }
  }
  __syncthreads();
  f32x4 zacc[4][4] = {};
  #pragma unroll
  for (int kc=0; kc<2; kc++){
    half8 va[4], pb[4];
    #pragma unroll
    for (int t4=0; t4<4; t4++){
      va[t4] = *(const half8*)(&Vt[wv][t4*16 + l15][kc*32 + quad*8]);
      pb[t4] = *(const half8*)(&Ps[wv][t4*16 + l15][kc*32 + quad*8]);
    }
    #pragma unroll
    for (int ti2=0; ti2<4; ti2++)
      #pragma unroll
      for (int tj=0; tj<4; tj++)
        zacc[ti2][tj] = mfma16(va[ti2], pb[tj], zacc[ti2][tj]);
  }
  __syncthreads();
  #pragma unroll
  for (int ti2=0; ti2<4; ti2++)
    #pragma unroll
    for (int tj=0; tj<4; tj++){
      int q = tj*16 + l15, d0 = ti2*16 + quad*4;
      half4 pk;
      #pragma unroll
      for (int i=0; i<4; i++) pk[i] = (f16)zacc[ti2][tj][i];
      *(half4*)(&Vt[wv][q][d0]) = pk;
    }
  __syncthreads();
  #pragma unroll
  for (int i=0; i<8; i++){
    int q = i*8 + (lane>>3), d0 = (lane&7)*8;
    *(uint4*)(qkv + ((size_t)n*64 + q)*1536 + h*64 + d0) = *(const uint4*)(&Vt[wv][q][d0]);
  }
}

// ---------------- LayerNorm over rows of 512 (wave per row) ----------------
__global__ __launch_bounds__(256) void ln_rows(
    const f16* __restrict__ X, f16* __restrict__ Y,
    const float* __restrict__ g, const float* __restrict__ b)
{
  int wv = threadIdx.x>>6, lane = threadIdx.x&63;
  size_t row = (size_t)blockIdx.x*4 + wv;
  half8 raw = *(const half8*)(X + row*512 + lane*8);
  float xv[8];
  #pragma unroll
  for (int j=0; j<8; j++) xv[j] = (float)raw[j];
  float s = 0.f;
  #pragma unroll
  for (int j=0; j<8; j++) s += xv[j];
  #pragma unroll
  for (int off=1; off<64; off<<=1) s += __shfl_xor(s, off, 64);
  float mean = s*(1.f/512.f);
  float vs = 0.f;
  #pragma unroll
  for (int j=0; j<8; j++){ float d = xv[j]-mean; vs += d*d; }
  #pragma unroll
  for (int off=1; off<64; off<<=1) vs += __shfl_xor(vs, off, 64);
  float rstd = rsqrtf(vs*(1.f/512.f) + 1e-5f);
  half8 o;
  #pragma unroll
  for (int j=0; j<8; j++){
    int c = lane*8 + j;
    o[j] = (f16)((xv[j]-mean)*rstd*g[c] + b[c]);
  }
  *(half8*)(Y + row*512 + lane*8) = o;
}

// ---------------- LN2 + masked mean pool + exists_bias + pos-encoding ----------------
__global__ __launch_bounds__(256) void pool_ln2(
    const f16* __restrict__ X, const int* __restrict__ mask,
    const float* __restrict__ g, const float* __restrict__ b, const float* __restrict__ eb,
    float* __restrict__ out, int nbase)
{
  __shared__ float mArr[64], rArr[64], vArr[64];
  const int tid = threadIdx.x, wv = tid>>6, lane = tid&63;
  const int n = blockIdx.x, ng = nbase + n, p = ng & 127;
  for (int j=0; j<16; j++){
    int l = wv*16 + j;
    half8 raw = *(const half8*)(X + ((size_t)n*64 + l)*512 + lane*8);
    float s=0.f, ss=0.f;
    #pragma unroll
    for (int jj=0; jj<8; jj++){ float f = (float)raw[jj]; s += f; ss += f*f; }
    #pragma unroll
    for (int off=1; off<64; off<<=1){ s += __shfl_xor(s, off, 64); ss += __shfl_xor(ss, off, 64); }
    if (lane == 0){
      float m = s*(1.f/512.f);
      mArr[l] = m; rArr[l] = rsqrtf(ss*(1.f/512.f) - m*m + 1e-5f);
    }
  }
  if (tid < 64) vArr[tid] = (mask[(size_t)ng*64 + tid] > 0) ? 1.f : 0.f;
  __syncthreads();
  float cnt = 0.f;
  #pragma unroll
  for (int l=0; l<64; l++) cnt += vArr[l];
  float denom = fmaxf(cnt, 1.f);
  float pexv = cnt > 0.f ? 1.f : 0.f;
  float a0=0.f, a1=0.f;
  for (int l=0; l<64; l++){
    float wgt = vArr[l], m = mArr[l], rs = rArr[l];
    float x0 = (float)X[((size_t)n*64+l)*512 + tid];
    float x1 = (float)X[((size_t)n*64+l)*512 + tid + 256];
    a0 += wgt*(x0-m)*rs; a1 += wgt*(x1-m)*rs;
  }
  #pragma unroll
  for (int k=0; k<2; k++){
    int c = tid + k*256;
    float acc = k ? a1 : a0;
    float fr = __expf(-(float)(c & ~1) * (9.210340371976184f/512.f));
    float ang = (float)p * fr;
    float pe = (c & 1) ? cosf(ang) : sinf(ang);
    float o = (g[c]*acc + b[c]*cnt)/denom + eb[c]*(1.f - pexv) + pe;
    out[(size_t)ng*512 + c] = o;
  }
}

__global__ __launch_bounds__(256) void cvt_f32_f16(const float* __restrict__ s, f16* __restrict__ d){
  int i = blockIdx.x*256 + threadIdx.x;
  d[i] = (f16)s[i];
}

// ---------------- graph attention on merged QKV (stride 1536), P=128 keys ----------------
__global__ __launch_bounds__(256) void attn_graph(
    f16* __restrict__ qkv, const float* __restrict__ pexists)
{
  __shared__ f16 Vt[64][136];
  __shared__ f16 Ps[4][32][136];
  __shared__ float pxs[128];
  const int tid = threadIdx.x, wv = tid>>6, lane = tid&63, l15 = lane&15, quad = lane>>4;
  const int b = blockIdx.x, h = blockIdx.y;
  if (tid < 128) pxs[tid] = pexists[b*128 + tid];
  const f16* Vb = qkv + 1024 + h*64;
  for (int i=0; i<32; i++){
    int e = tid + i*256, k = e>>6, d = e&63;
    Vt[d][k] = Vb[((size_t)b*128 + k)*1536 + d];
  }
  __syncthreads();
  const f16* Qb = qkv + h*64;
  const f16* Kb = qkv + 512 + h*64;
  const int qb = wv*32;
  f32x4 sacc[2][8] = {};
  #pragma unroll
  for (int kc=0; kc<2; kc++){
    half8 af[2], bf[8];
    #pragma unroll
    for (int ti=0; ti<2; ti++)
      af[ti] = *(const half8*)(Qb + ((size_t)b*128 + qb + ti*16 + l15)*1536 + kc*32 + quad*8);
    #pragma unroll
    for (int tj=0; tj<8; tj++)
      bf[tj] = *(const half8*)(Kb + ((size_t)b*128 + tj*16 + l15)*1536 + kc*32 + quad*8);
    #pragma unroll
    for (int ti=0; ti<2; ti++)
      #pragma unroll
      for (int tj=0; tj<8; tj++)
        sacc[ti][tj] = mfma16(af[ti], bf[tj], sacc[ti][tj]);
  }
  #pragma unroll
  for (int ti=0; ti<2; ti++){
    #pragma unroll
    for (int i=0; i<4; i++){
      int q = qb + ti*16 + quad*4 + i;
      float mx = -1e30f;
      #pragma unroll
      for (int tj=0; tj<8; tj++){
        int col = tj*16 + l15;
        int dd = q - col; if (dd < 0) dd = -dd;
        float tb = __logf(__expf(-(float)dd) + 1e-12f);
        float sv = sacc[ti][tj][i]*0.125f + tb + (pxs[col] > 0.f ? 0.f : -1e9f);
        sacc[ti][tj][i] = sv;
        mx = fmaxf(mx, sv);
      }
      #pragma unroll
      for (int off=1; off<16; off<<=1) mx = fmaxf(mx, __shfl_xor(mx, off, 64));
      float sum = 0.f;
      #pragma unroll
      for (int tj=0; tj<8; tj++){
        float pv = __expf(sacc[ti][tj][i] - mx);
        sacc[ti][tj][i] = pv; sum += pv;
      }
      #pragma unroll
      for (int off=1; off<16; off<<=1) sum += __shfl_xor(sum, off, 64);
      float inv = 1.f/sum;
      int ql = ti*16 + quad*4 + i;
      #pragma unroll
      for (int tj=0; tj<8; tj++)
        Ps[wv][ql][tj*16 + l15] = (f16)(sacc[ti][tj][i]*inv);
    }
  }
  __syncthreads();
  f32x4 zacc[4][2] = {};
  #pragma unroll
  for (int kc=0; kc<4; kc++){
    half8 va[4], pb[2];
    #pragma unroll
    for (int ti2=0; ti2<4; ti2++)
      va[ti2] = *(const half8*)(&Vt[ti2*16 + l15][kc*32 + quad*8]);
    #pragma unroll
    for (int tjq=0; tjq<2; tjq++)
      pb[tjq] = *(const half8*)(&Ps[wv][tjq*16 + l15][kc*32 + quad*8]);
    #pragma unroll
    for (int ti2=0; ti2<4; ti2++)
      #pragma unroll
      for (int tjq=0; tjq<2; tjq++)
        zacc[ti2][tjq] = mfma16(va[ti2], pb[tjq], zacc[ti2][tjq]);
  }
  __syncthreads();
  #pragma unroll
  for (int ti2=0; ti2<4; ti2++)
    #pragma unroll
    for (int tjq=0; tjq<2; tjq++){
      int ql = tjq*16 + l15, d0 = ti2*16 + quad*4;
      half4 pk;
      #pragma unroll
      for (int i=0; i<4; i++) pk[i] = (f16)zacc[ti2][tjq][i];
      *(half4*)(&Ps[wv][ql][d0]) = pk;
    }
  __syncthreads();
  {
    int q = tid>>1, hf = tid&1;
    const f16* src = &Ps[q>>5][q&31][hf*32];
    #pragma unroll
    for (int j=0; j<4; j++)
      *(uint4*)(qkv + ((size_t)b*128 + q)*1536 + h*64 + hf*32 + j*8) = *(const uint4*)(src + j*8);
  }
}

// ---------------- launcher ----------------
extern "C" void kernel_launch(void* const* d_in, const int* in_sizes, int n_in,
                              void* d_out, int out_size, void* d_ws, size_t ws_size,
                              hipStream_t stream)
{
  (void)in_sizes; (void)n_in; (void)out_size; (void)ws_size;
  const float* x    = (const float*)d_in[0];
  const float* tt   = (const float*)d_in[1];
  const int*   mask = (const int*)  d_in[2];
  const float* tsw  = (const float*)d_in[3];
  const float* tsb  = (const float*)d_in[4];
  const float* tpw  = (const float*)d_in[5];
  const float* tpb  = (const float*)d_in[6];
  const float* inpw = (const float*)d_in[7];
  const float* inpb = (const float*)d_in[8];
  const float* wq   = (const float*)d_in[9];
  const float* bq   = (const float*)d_in[10];
  const float* wk   = (const float*)d_in[11];
  const float* bk   = (const float*)d_in[12];
  const float* wv   = (const float*)d_in[13];
  const float* bv   = (const float*)d_in[14];
  const float* wo   = (const float*)d_in[15];
  const float* bo   = (const float*)d_in[16];
  const float* w1   = (const float*)d_in[17];
  const float* b1   = (const float*)d_in[18];
  const float* w2   = (const float*)d_in[19];
  const float* b2   = (const float*)d_in[20];
  const float* ln1g = (const float*)d_in[21];
  const float* ln1b = (const float*)d_in[22];
  const float* ln2g = (const float*)d_in[23];
  const float* ln2b = (const float*)d_in[24];
  const float* eb   = (const float*)d_in[25];
  const float* gwq  = (const float*)d_in[26];
  const float* gbq  = (const float*)d_in[27];
  const float* gwk  = (const float*)d_in[28];
  const float* gbk  = (const float*)d_in[29];
  const float* gwv  = (const float*)d_in[30];
  const float* gbv  = (const float*)d_in[31];
  const float* gwo  = (const float*)d_in[32];
  const float* gbo  = (const float*)d_in[33];
  float* out = (float*)d_out;

  char* wp = (char*)d_ws;
  auto alloc = [&](size_t bytes)->char*{
    char* p = wp; wp += (bytes + 255) & ~(size_t)255; return p;
  };
  f16*   wbf   = (f16*)  alloc((size_t)WBF_TOT*2);
  float* mb    = (float*)alloc((size_t)NTOK*64*4);
  float* pex   = (float*)alloc((size_t)NTOK*4);
  float* biasb = (float*)alloc((size_t)3*1536*4);
  f16*   ptsb  = (f16*)  alloc((size_t)CH*64*128*2);
  f16*   bufA  = (f16*)  alloc((size_t)CH*64*512*2);   // h0 / h1; stage-3: hbf
  f16*   bufB  = (f16*)  alloc((size_t)CH*64*512*2);   // ln1 out / ffn2 out; stage-3: qkvg
  f16*   bufC  = (f16*)  alloc((size_t)CH*64*512*2);   // ffn1 out
  f16*   qkv   = (f16*)  alloc((size_t)CH*64*1536*2);  // merged q|k|v (z overwrites q)
  // total ~219 MiB

  conv_weights<<<dim3(1024,16),256,0,stream>>>(inpw,wq,wk,wv,wo,w1,w2,gwq,gwk,gwv,gwo,wbf,
                                               bq,bk,bv,gbq,gbk,gbv,biasb);
  build_mask<<<NTOK/4,256,0,stream>>>(mask, mb, pex);

  const int MB = CH*64/128;   // 256 m-blocks per chunk
  for (int ch=0; ch<NCHUNK; ch++){
    int nbase = ch*CH;
    int rowbase = nbase*64;
    pts_build<<<CH*64*128/256,256,0,stream>>>(x,tt,tsw,tsb,tpw,tpb,ptsb,rowbase);
    // h0 = pts @ inp_w^T + b (zero row0 of empty patches)
    gemm128<0,false,false,true ><<<dim3(MB,4),256,0,stream>>>(ptsb, wbf+OFF_INPW, inpb, bufA, nullptr, pex, 128, 128, 512, nbase);
    // fused q|k|v
    gemm128<0,false,false,false><<<dim3(MB,12),256,0,stream>>>(bufA, wbf+OFF_WQKV, biasb, qkv, nullptr, nullptr, 512, 512, 1536, 0);
    attn_patch<<<dim3(CH,4),128,0,stream>>>(qkv, mb, nbase);
    // out-proj + residual(h0), in place on bufA; A = z (q-region of qkv, lda 1536)
    gemm128<1,false,false,false><<<dim3(MB,4),256,0,stream>>>(qkv, wbf+OFF_WO, bo, bufA, bufA, nullptr, 512, 1536, 512, 0);
    ln_rows<<<CH*64/4,256,0,stream>>>(bufA, bufB, ln1g, ln1b);
    gemm128<0,true ,false,false><<<dim3(MB,4),256,0,stream>>>(bufB, wbf+OFF_W1, b1, bufC, nullptr, nullptr, 512, 512, 512, 0);
    gemm128<1,false,false,false><<<dim3(MB,4),256,0,stream>>>(bufC, wbf+OFF_W2, b2, bufB, bufB, nullptr, 512, 512, 512, 0);
    pool_ln2<<<CH,256,0,stream>>>(bufB, mask, ln2g, ln2b, eb, out, nbase);
  }

  f16* hbf  = bufA;              // reuse stage-2 buffers
  f16* qkvg = bufB;
  for (int li=0; li<2; li++){
    cvt_f32_f16<<<NTOK*512/256,256,0,stream>>>(out, hbf);
    gemm128<0,false,false,false><<<dim3(32,12),256,0,stream>>>(hbf, wbf+OFF_GW + (size_t)li*4*512*512, biasb + 1536*(1+li), qkvg, nullptr, nullptr, 512, 512, 1536, 0);
    attn_graph<<<dim3(32,8),256,0,stream>>>(qkvg, pex);
    // h += (z @ gwo^T + gbo) * pexists (in place on f32 d_out)
    gemm128<2,false,true ,false><<<dim3(32,4),256,0,stream>>>(qkvg, wbf+OFF_GW + (size_t)(li*4+3)*512*512, gbo+li*512, out, out, pex, 512, 1536, 512, 0);
  }
}